// Round 12
// baseline (451.788 us; speedup 1.0000x reference)
//
#include <hip/hip_runtime.h>

typedef __attribute__((ext_vector_type(8))) short short8;
typedef __attribute__((ext_vector_type(4))) float f32x4;
typedef unsigned short u16;
typedef unsigned int u32;

#define DEVI __device__ __forceinline__

// round-to-nearest-even f32 -> bf16 bits
DEVI u16 f2bf(float f) {
    union { float f; u32 u; } v; v.f = f;
    u32 r = v.u + 0x7FFFu + ((v.u >> 16) & 1u);
    return (u16)(r >> 16);
}

// ---------------- merged f32 -> bf16 convert for 3 arrays ----------------
__global__ void cvt3_kernel(const float* __restrict__ a, u16* __restrict__ oa, int na4,
                            const float* __restrict__ b, u16* __restrict__ ob, int nb4,
                            const float* __restrict__ c, u16* __restrict__ oc, int nc4) {
    int total = na4 + nb4 + nc4;
    int stride = gridDim.x * blockDim.x;
    for (int i = blockIdx.x * blockDim.x + threadIdx.x; i < total; i += stride) {
        const float* in; u16* out; int j = i;
        if (j < na4) { in = a; out = oa; }
        else if ((j -= na4) < nb4) { in = b; out = ob; }
        else { j -= nb4; in = c; out = oc; }
        float4 v = reinterpret_cast<const float4*>(in)[j];
        ushort4 o;
        o.x = f2bf(v.x); o.y = f2bf(v.y); o.z = f2bf(v.z); o.w = f2bf(v.w);
        reinterpret_cast<ushort4*>(out)[j] = o;
    }
}

// ---------------- embed + pos + leaky1 -> bf16 A ----------------
__global__ __launch_bounds__(64)
void embed_leaky_kernel(const int* __restrict__ x, const float* __restrict__ emb,
                        const float* __restrict__ pos, const float* __restrict__ beta,
                        u16* __restrict__ Aout) {
    __shared__ int xs[128];
    int gtid = blockIdx.x * 64 + threadIdx.x;
    int b = gtid >> 9;      // constant per block
    int h = gtid & 511;
    for (int i = threadIdx.x; i < 128; i += 64) xs[i] = x[i * 32 + b];
    __syncthreads();
    float be = beta[h];
    float mem = 0.f;
    for (int t0 = 0; t0 < 128; t0 += 8) {
        float e[8];
#pragma unroll
        for (int j = 0; j < 8; ++j)
            e[j] = emb[(size_t)xs[t0 + j] * 512 + h] + pos[(t0 + j) * 512 + h];
#pragma unroll
        for (int j = 0; j < 8; ++j) {
            mem = be * mem + e[j];
            Aout[(size_t)((t0 + j) * 32 + b) * 512 + h] = f2bf(mem);
        }
    }
}

// ---------------- leaky over f32 input -> bf16 A ----------------
__global__ __launch_bounds__(64)
void leaky_bf16_kernel(const float* __restrict__ in, const float* __restrict__ beta,
                       u16* __restrict__ Aout) {
    int gtid = blockIdx.x * 64 + threadIdx.x;
    int b = gtid >> 9;
    int h = gtid & 511;
    float be = beta[h];
    float mem = 0.f;
    for (int t0 = 0; t0 < 128; t0 += 8) {
        float v[8];
#pragma unroll
        for (int j = 0; j < 8; ++j)
            v[j] = in[(size_t)((t0 + j) * 32 + b) * 512 + h];
#pragma unroll
        for (int j = 0; j < 8; ++j) {
            mem = be * mem + v[j];
            Aout[(size_t)((t0 + j) * 32 + b) * 512 + h] = f2bf(mem);
        }
    }
}

// ---------------- 128x128 bf16 GEMM (round-5 proven; used for fc2/fc3) ----
template<bool RELU>
__global__ __launch_bounds__(256)
void gemm_bt_128(const u16* __restrict__ A, const u16* __restrict__ B,
                 const float* __restrict__ bias, float* __restrict__ C,
                 int M, int N, int K, int tiles_n) {
    __shared__ alignas(16) char smem[32 * 132 * 4];
    u16* As = (u16*)smem;
    u16* Bs = (u16*)(smem + 8192);
    float* Ep = (float*)smem;

    const int tid = threadIdx.x;
    int bm = blockIdx.x / tiles_n;
    int bn = blockIdx.x % tiles_n;
    const int wv = tid >> 6;
    const int lane = tid & 63;
    const int wr = wv >> 1, wc = wv & 1;
    const int lrow = lane & 15;
    const int kg = lane >> 4;
    const int kgp = kg ^ ((lrow >> 1) & 3);

    f32x4 acc[4][4];
#pragma unroll
    for (int i = 0; i < 4; ++i)
#pragma unroll
        for (int j = 0; j < 4; ++j) acc[i][j] = (f32x4){0.f, 0.f, 0.f, 0.f};

    const size_t rowb = (size_t)K * 2;
    const char* Ab = (const char*)A + (size_t)(bm * 128) * rowb;
    const char* Bb = (const char*)B + (size_t)(bn * 128) * rowb;

    float bv[4];
#pragma unroll
    for (int ni = 0; ni < 4; ++ni)
        bv[ni] = bias[bn * 128 + wc * 64 + ni * 16 + lrow];

    for (int k0 = 0; k0 < K; k0 += 32) {
        int k2 = k0 << 1;
#pragma unroll
        for (int r = 0; r < 2; ++r) {
            int s = r * 256 + tid;
            int row = s >> 2;
            int k16g = (s & 3) ^ ((row >> 1) & 3);
            size_t goff = (size_t)row * rowb + k2 + k16g * 16;
            __builtin_amdgcn_global_load_lds(
                (const __attribute__((address_space(1))) void*)(Ab + goff),
                (__attribute__((address_space(3))) void*)((char*)As + s * 16), 16, 0, 0);
            __builtin_amdgcn_global_load_lds(
                (const __attribute__((address_space(1))) void*)(Bb + goff),
                (__attribute__((address_space(3))) void*)((char*)Bs + s * 16), 16, 0, 0);
        }
        __syncthreads();

        short8 a[4], b[4];
#pragma unroll
        for (int mi = 0; mi < 4; ++mi)
            a[mi] = *(const short8*)&As[(wr * 64 + mi * 16 + lrow) * 32 + kgp * 8];
#pragma unroll
        for (int ni = 0; ni < 4; ++ni)
            b[ni] = *(const short8*)&Bs[(wc * 64 + ni * 16 + lrow) * 32 + kgp * 8];
#pragma unroll
        for (int mi = 0; mi < 4; ++mi)
#pragma unroll
            for (int ni = 0; ni < 4; ++ni)
                acc[mi][ni] = __builtin_amdgcn_mfma_f32_16x16x32_bf16(a[mi], b[ni], acc[mi][ni], 0, 0, 0);
        __syncthreads();
    }

#pragma unroll
    for (int mi = 0; mi < 4; ++mi) {
#pragma unroll
        for (int ni = 0; ni < 4; ++ni) {
            int c = wc * 64 + ni * 16 + lrow;
            f32x4 v = acc[mi][ni];
#pragma unroll
            for (int j = 0; j < 4; ++j) {
                float o = v[j] + bv[ni];
                if (RELU) o = fmaxf(o, 0.f);
                Ep[(wr * 16 + kg * 4 + j) * 132 + c] = o;
            }
        }
        __syncthreads();
#pragma unroll
        for (int rr = 0; rr < 8; ++rr) {
            int rl = wv * 8 + rr;
            int grow = bm * 128 + (rl >> 4) * 64 + mi * 16 + (rl & 15);
            size_t base = (size_t)grow * N + bn * 128;
#pragma unroll
            for (int hh = 0; hh < 2; ++hh) {
                int c = hh * 64 + lane;
                C[base + c] = Ep[rl * 132 + c];
            }
        }
        if (mi < 3) __syncthreads();
    }
}

// -------- persistent 128x256 bf16 GEMM, tri-buffer, rolling pipeline ------
// Grid = 512 (2 blocks/CU). 6304 tiles = 8 XCD x 788; block (xcd,slot) does
// tiles xcd*788 + j*64 + slot (bn-major order -> XCD-local B panels).
// Continuous compute stream g (16 K-slabs per tile); buf = g%3; stage(g+2)
// issued at iter g -> pipeline never drains across tile boundaries; the two
// co-resident blocks drift out of phase (epilogue overlaps neighbor's MFMA).
// Counted vmcnt: k<=1 -> 7 (4 clamped bias loads in FIFO), else 3, last 0.
// LDS granule-XOR (slice ^= row&3) on stage-source + frag-read: 2-way = free.
// Epilogue per tile: 8 chunks [16][260] f32 in the just-freed buffer (j%3),
// 16B/lane NT stores.
__global__ __launch_bounds__(512, 4)
void gemm_bt_v(const u16* __restrict__ A, const u16* __restrict__ B,
               const float* __restrict__ bias, float* __restrict__ C,
               int M, int N, int K) {
    extern __shared__ char smem[];   // 3 x 24576

    const int tid = threadIdx.x;
    const int xcd = blockIdx.x & 7;
    const int slot = blockIdx.x >> 3;           // 0..63
    const int xbase = xcd * 788;
    const int ntiles = (slot < 20) ? 13 : 12;   // 788 = 12*64 + 20
    const int ntot = ntiles << 4;

    const int wv = tid >> 6;
    const int lane = tid & 63;
    const int wr = wv >> 2;        // 0..1 (M half: 64 rows)
    const int wc = wv & 3;         // 0..3 (N quarter: 64 cols)
    const int lrow = lane & 15;
    const int kg = lane >> 4;      // 0..3
    const int kgx = kg ^ (lrow & 3);  // XOR'd slice slot for frag reads

    const size_t rowb = (size_t)K * 2;
    const char* Abase = (const char*)A;
    const char* Bbase = (const char*)B;

    f32x4 acc[4][4];
#pragma unroll
    for (int i = 0; i < 4; ++i)
#pragma unroll
        for (int j = 0; j < 4; ++j) acc[i][j] = (f32x4){0.f, 0.f, 0.f, 0.f};

    // stage slab for stream index g into buffer buf (lane-linear LDS dst;
    // global source granule-XOR permuted within each 64B line)
    auto STAGE = [&](int g, int buf) {
        int j = g >> 4;
        int t = xbase + (j << 6) + slot;
        int bm = t & 31, bn = t >> 5;
        const char* Ab = Abase + ((size_t)bm << 7) * rowb;
        const char* Bb = Bbase + ((size_t)bn << 8) * rowb;
        int k2 = (g & 15) << 6;        // byte col of slab
        char* dA = smem + buf * 24576;
        char* dB = dA + 8192;
        {
            int s = tid;
            int row = s >> 2, ls = s & 3;
            int gsl = ls ^ (row & 3);
            __builtin_amdgcn_global_load_lds(
                (const __attribute__((address_space(1))) void*)(Ab + (size_t)row * rowb + k2 + gsl * 16),
                (__attribute__((address_space(3))) void*)(dA + s * 16), 16, 0, 0);
        }
#pragma unroll
        for (int j2 = 0; j2 < 2; ++j2) {
            int s = j2 * 512 + tid;
            int row = s >> 2, ls = s & 3;
            int gsl = ls ^ (row & 3);
            __builtin_amdgcn_global_load_lds(
                (const __attribute__((address_space(1))) void*)(Bb + (size_t)row * rowb + k2 + gsl * 16),
                (__attribute__((address_space(3))) void*)(dB + s * 16), 16, 0, 0);
        }
    };

    auto COMPUTE = [&](int buf) {
        const char* Ah = smem + buf * 24576;
        const char* Bh = Ah + 8192;
        short8 a[4], b[4];
#pragma unroll
        for (int mi = 0; mi < 4; ++mi) {
            int rr = wr * 64 + mi * 16 + lrow;
            a[mi] = *(const short8*)(Ah + rr * 64 + kgx * 16);
        }
#pragma unroll
        for (int ni = 0; ni < 4; ++ni) {
            int rr = wc * 64 + ni * 16 + lrow;
            b[ni] = *(const short8*)(Bh + rr * 64 + kgx * 16);
        }
        __builtin_amdgcn_s_setprio(1);
#pragma unroll
        for (int mi = 0; mi < 4; ++mi)
#pragma unroll
            for (int ni = 0; ni < 4; ++ni)
                acc[mi][ni] = __builtin_amdgcn_mfma_f32_16x16x32_bf16(a[mi], b[ni], acc[mi][ni], 0, 0, 0);
        __builtin_amdgcn_s_setprio(0);
    };

    // prologue: stages first, then bias (FIFO: s0, s1, bias)
    STAGE(0, 0);
    STAGE(1, 1);
    __builtin_amdgcn_sched_barrier(0);
    float bv[4];
    {
        int t0 = xbase + slot;
        int bn0 = t0 >> 5;
#pragma unroll
        for (int ni = 0; ni < 4; ++ni) {
            int col = bn0 * 256 + wc * 64 + ni * 16 + lrow;
            bv[ni] = bias[col < N ? col : (N - 1)];
        }
    }
    __builtin_amdgcn_sched_barrier(0);

    for (int g = 0; g < ntot; ++g) {
        int k = g & 15;
        int bufc = g % 3;
        if (g == ntot - 1)  asm volatile("s_waitcnt vmcnt(0)" ::: "memory");
        else if (k <= 1)    asm volatile("s_waitcnt vmcnt(7)" ::: "memory");
        else                asm volatile("s_waitcnt vmcnt(3)" ::: "memory");
        __builtin_amdgcn_s_barrier();
        __builtin_amdgcn_sched_barrier(0);
        if (g + 2 < ntot) STAGE(g + 2, (g + 2) % 3);
        COMPUTE(bufc);

        if (k == 15) {
            int j = g >> 4;
            // next tile's bias (pinned AFTER this iter's stage in FIFO)
            __builtin_amdgcn_sched_barrier(0);
            float bvn[4];
            {
                int t1 = xbase + ((j + 1) << 6) + slot;   // valid only if j+1<ntiles
                int bn1 = (j + 1 < ntiles) ? (t1 >> 5) : 0;
#pragma unroll
                for (int ni = 0; ni < 4; ++ni) {
                    int col = bn1 * 256 + wc * 64 + ni * 16 + lrow;
                    bvn[ni] = bias[col < N ? col : (N - 1)];
                }
            }
            // epilogue for tile j; Ep = just-freed buffer (j % 3)
            int t = xbase + (j << 6) + slot;
            int bm = t & 31, bn = t >> 5;
            float* Ep = (float*)(smem + bufc * 24576);
            __syncthreads();
#pragma unroll
            for (int ch = 0; ch < 8; ++ch) {
                if (wr == (ch >> 2)) {
                    int mi = ch & 3;
#pragma unroll
                    for (int ni = 0; ni < 4; ++ni) {
                        int c = wc * 64 + ni * 16 + lrow;
                        f32x4 v = acc[mi][ni];
#pragma unroll
                        for (int j2 = 0; j2 < 4; ++j2)
                            Ep[(kg * 4 + j2) * 260 + c] = v[j2] + bv[ni];
                    }
                }
                __syncthreads();
#pragma unroll
                for (int rr = 0; rr < 2; ++rr) {
                    int rl = wv * 2 + rr;
                    int grow = bm * 128 + ch * 16 + rl;
                    int gc0 = bn * 256 + lane * 4;
                    f32x4 v = *(const f32x4*)&Ep[rl * 260 + lane * 4];
                    if (gc0 + 3 < N) {
                        __builtin_nontemporal_store(v, (f32x4*)&C[(size_t)grow * N + gc0]);
                    } else {
#pragma unroll
                        for (int e = 0; e < 4; ++e)
                            if (gc0 + e < N)
                                __builtin_nontemporal_store(v[e], &C[(size_t)grow * N + gc0 + e]);
                    }
                }
                if (ch < 7) __syncthreads();
            }
            // reset for next tile
#pragma unroll
            for (int i = 0; i < 4; ++i)
#pragma unroll
                for (int j2 = 0; j2 < 4; ++j2) acc[i][j2] = (f32x4){0.f, 0.f, 0.f, 0.f};
#pragma unroll
            for (int ni = 0; ni < 4; ++ni) bv[ni] = bvn[ni];
        }
    }
}

extern "C" void kernel_launch(void* const* d_in, const int* in_sizes, int n_in,
                              void* d_out, int out_size, void* d_ws, size_t ws_size,
                              hipStream_t stream) {
    const int* x    = (const int*)d_in[0];
    const float* emb = (const float*)d_in[1];
    const float* pos = (const float*)d_in[2];
    const float* b1 = (const float*)d_in[3];
    const float* b2 = (const float*)d_in[4];
    const float* b3 = (const float*)d_in[5];
    const float* w2 = (const float*)d_in[6];
    const float* fb2 = (const float*)d_in[7];
    const float* w3 = (const float*)d_in[8];
    const float* fb3 = (const float*)d_in[9];
    const float* wo = (const float*)d_in[10];
    const float* fbo = (const float*)d_in[11];
    float* out = (float*)d_out;

    const int V = 50257;
    const int TN = 197;                 // 256-col tiles for vocab
    const int Vpad = TN * 256;          // 50432

    static bool lds_cap_set = false;
    if (!lds_cap_set) {
        hipFuncSetAttribute((const void*)gemm_bt_v,
                            hipFuncAttributeMaxDynamicSharedMemorySize, 73728);
        lds_cap_set = true;
    }

    // workspace layout
    char* p = (char*)d_ws;
    u16* WO = (u16*)p;  p += (size_t)Vpad * 512 * 2;   // 51.6 MB
    u16* W2 = (u16*)p;  p += (size_t)512 * 512 * 2;
    u16* W3 = (u16*)p;  p += (size_t)512 * 512 * 2;
    u16* Abf = (u16*)p; p += (size_t)4096 * 512 * 2;   // bf16 activations [4096,512]
    float* Hb = (float*)p;                             // f32 activations [4096,512]

    // weight conversions f32 -> bf16 (merged)
    cvt3_kernel<<<dim3(2048), dim3(256), 0, stream>>>(
        wo, WO, V * 512 / 4, w2, W2, 512 * 512 / 4, w3, W3, 512 * 512 / 4);

    // embed + pos + leaky1 -> Abf
    embed_leaky_kernel<<<dim3(256), dim3(64), 0, stream>>>(x, emb, pos, b1, Abf);

    // fc2 + relu -> Hb
    gemm_bt_128<true><<<dim3(32 * 4), dim3(256), 0, stream>>>(Abf, W2, fb2, Hb, 4096, 512, 512, 4);
    // leaky2 -> Abf
    leaky_bf16_kernel<<<dim3(256), dim3(64), 0, stream>>>(Hb, b2, Abf);
    // fc3 + relu -> Hb
    gemm_bt_128<true><<<dim3(32 * 4), dim3(256), 0, stream>>>(Abf, W3, fb3, Hb, 4096, 512, 512, 4);
    // leaky3 -> Abf
    leaky_bf16_kernel<<<dim3(256), dim3(64), 0, stream>>>(Hb, b3, Abf);
    // vocab projection -> out: persistent 128x256, rolling tri-buffer pipeline
    gemm_bt_v<<<dim3(512), dim3(512), 73728, stream>>>(Abf, WO, fbo, out, 4096, V, 512);
}

// Round 13
// 401.340 us; speedup vs baseline: 1.1257x; 1.1257x over previous
//
#include <hip/hip_runtime.h>

typedef __attribute__((ext_vector_type(8))) short short8;
typedef __attribute__((ext_vector_type(4))) float f32x4;
typedef unsigned short u16;
typedef unsigned int u32;

#define DEVI __device__ __forceinline__

// round-to-nearest-even f32 -> bf16 bits
DEVI u16 f2bf(float f) {
    union { float f; u32 u; } v; v.f = f;
    u32 r = v.u + 0x7FFFu + ((v.u >> 16) & 1u);
    return (u16)(r >> 16);
}

// ---------------- merged f32 -> bf16 convert for 3 arrays ----------------
__global__ void cvt3_kernel(const float* __restrict__ a, u16* __restrict__ oa, int na4,
                            const float* __restrict__ b, u16* __restrict__ ob, int nb4,
                            const float* __restrict__ c, u16* __restrict__ oc, int nc4) {
    int total = na4 + nb4 + nc4;
    int stride = gridDim.x * blockDim.x;
    for (int i = blockIdx.x * blockDim.x + threadIdx.x; i < total; i += stride) {
        const float* in; u16* out; int j = i;
        if (j < na4) { in = a; out = oa; }
        else if ((j -= na4) < nb4) { in = b; out = ob; }
        else { j -= nb4; in = c; out = oc; }
        float4 v = reinterpret_cast<const float4*>(in)[j];
        ushort4 o;
        o.x = f2bf(v.x); o.y = f2bf(v.y); o.z = f2bf(v.z); o.w = f2bf(v.w);
        reinterpret_cast<ushort4*>(out)[j] = o;
    }
}

// ---------------- embed + pos + leaky1 -> bf16 A ----------------
__global__ __launch_bounds__(64)
void embed_leaky_kernel(const int* __restrict__ x, const float* __restrict__ emb,
                        const float* __restrict__ pos, const float* __restrict__ beta,
                        u16* __restrict__ Aout) {
    __shared__ int xs[128];
    int gtid = blockIdx.x * 64 + threadIdx.x;
    int b = gtid >> 9;      // constant per block
    int h = gtid & 511;
    for (int i = threadIdx.x; i < 128; i += 64) xs[i] = x[i * 32 + b];
    __syncthreads();
    float be = beta[h];
    float mem = 0.f;
    for (int t0 = 0; t0 < 128; t0 += 8) {
        float e[8];
#pragma unroll
        for (int j = 0; j < 8; ++j)
            e[j] = emb[(size_t)xs[t0 + j] * 512 + h] + pos[(t0 + j) * 512 + h];
#pragma unroll
        for (int j = 0; j < 8; ++j) {
            mem = be * mem + e[j];
            Aout[(size_t)((t0 + j) * 32 + b) * 512 + h] = f2bf(mem);
        }
    }
}

// ---------------- leaky over f32 input -> bf16 A ----------------
__global__ __launch_bounds__(64)
void leaky_bf16_kernel(const float* __restrict__ in, const float* __restrict__ beta,
                       u16* __restrict__ Aout) {
    int gtid = blockIdx.x * 64 + threadIdx.x;
    int b = gtid >> 9;
    int h = gtid & 511;
    float be = beta[h];
    float mem = 0.f;
    for (int t0 = 0; t0 < 128; t0 += 8) {
        float v[8];
#pragma unroll
        for (int j = 0; j < 8; ++j)
            v[j] = in[(size_t)((t0 + j) * 32 + b) * 512 + h];
#pragma unroll
        for (int j = 0; j < 8; ++j) {
            mem = be * mem + v[j];
            Aout[(size_t)((t0 + j) * 32 + b) * 512 + h] = f2bf(mem);
        }
    }
}

// ---------------- 128x128 bf16 GEMM (round-5 proven; used for fc2/fc3) ----
template<bool RELU>
__global__ __launch_bounds__(256)
void gemm_bt_128(const u16* __restrict__ A, const u16* __restrict__ B,
                 const float* __restrict__ bias, float* __restrict__ C,
                 int M, int N, int K, int tiles_n) {
    __shared__ alignas(16) char smem[32 * 132 * 4];
    u16* As = (u16*)smem;
    u16* Bs = (u16*)(smem + 8192);
    float* Ep = (float*)smem;

    const int tid = threadIdx.x;
    int bm = blockIdx.x / tiles_n;
    int bn = blockIdx.x % tiles_n;
    const int wv = tid >> 6;
    const int lane = tid & 63;
    const int wr = wv >> 1, wc = wv & 1;
    const int lrow = lane & 15;
    const int kg = lane >> 4;
    const int kgp = kg ^ ((lrow >> 1) & 3);

    f32x4 acc[4][4];
#pragma unroll
    for (int i = 0; i < 4; ++i)
#pragma unroll
        for (int j = 0; j < 4; ++j) acc[i][j] = (f32x4){0.f, 0.f, 0.f, 0.f};

    const size_t rowb = (size_t)K * 2;
    const char* Ab = (const char*)A + (size_t)(bm * 128) * rowb;
    const char* Bb = (const char*)B + (size_t)(bn * 128) * rowb;

    float bv[4];
#pragma unroll
    for (int ni = 0; ni < 4; ++ni)
        bv[ni] = bias[bn * 128 + wc * 64 + ni * 16 + lrow];

    for (int k0 = 0; k0 < K; k0 += 32) {
        int k2 = k0 << 1;
#pragma unroll
        for (int r = 0; r < 2; ++r) {
            int s = r * 256 + tid;
            int row = s >> 2;
            int k16g = (s & 3) ^ ((row >> 1) & 3);
            size_t goff = (size_t)row * rowb + k2 + k16g * 16;
            __builtin_amdgcn_global_load_lds(
                (const __attribute__((address_space(1))) void*)(Ab + goff),
                (__attribute__((address_space(3))) void*)((char*)As + s * 16), 16, 0, 0);
            __builtin_amdgcn_global_load_lds(
                (const __attribute__((address_space(1))) void*)(Bb + goff),
                (__attribute__((address_space(3))) void*)((char*)Bs + s * 16), 16, 0, 0);
        }
        __syncthreads();

        short8 a[4], b[4];
#pragma unroll
        for (int mi = 0; mi < 4; ++mi)
            a[mi] = *(const short8*)&As[(wr * 64 + mi * 16 + lrow) * 32 + kgp * 8];
#pragma unroll
        for (int ni = 0; ni < 4; ++ni)
            b[ni] = *(const short8*)&Bs[(wc * 64 + ni * 16 + lrow) * 32 + kgp * 8];
#pragma unroll
        for (int mi = 0; mi < 4; ++mi)
#pragma unroll
            for (int ni = 0; ni < 4; ++ni)
                acc[mi][ni] = __builtin_amdgcn_mfma_f32_16x16x32_bf16(a[mi], b[ni], acc[mi][ni], 0, 0, 0);
        __syncthreads();
    }

#pragma unroll
    for (int mi = 0; mi < 4; ++mi) {
#pragma unroll
        for (int ni = 0; ni < 4; ++ni) {
            int c = wc * 64 + ni * 16 + lrow;
            f32x4 v = acc[mi][ni];
#pragma unroll
            for (int j = 0; j < 4; ++j) {
                float o = v[j] + bv[ni];
                if (RELU) o = fmaxf(o, 0.f);
                Ep[(wr * 16 + kg * 4 + j) * 132 + c] = o;
            }
        }
        __syncthreads();
#pragma unroll
        for (int rr = 0; rr < 8; ++rr) {
            int rl = wv * 8 + rr;
            int grow = bm * 128 + (rl >> 4) * 64 + mi * 16 + (rl & 15);
            size_t base = (size_t)grow * N + bn * 128;
#pragma unroll
            for (int hh = 0; hh < 2; ++hh) {
                int c = hh * 64 + lane;
                C[base + c] = Ep[rl * 132 + c];
            }
        }
        if (mi < 3) __syncthreads();
    }
}

// ---------------- 128x256 bf16 GEMM, BK=32, tri-buffer, 2 blocks/CU (vocab)
// Round-11 proven structure + granule-XOR LDS swizzle (the one change):
// stage source slice = ls ^ (row&3) within each 64B line (coalescing kept,
// LDS dst lane-linear = m104-safe); frag read slot = kg ^ (lrow&3).
// This spreads each 8-lane ds_read_b128 phase over 4 distinct 16B columns
// (2 lanes/bank = free) instead of 2 (4-way conflict).
__global__ __launch_bounds__(512, 4)
void gemm_bt_v(const u16* __restrict__ A, const u16* __restrict__ B,
               const float* __restrict__ bias, float* __restrict__ C,
               int M, int N, int K, int tiles_m, int tiles_n) {
    extern __shared__ char smem[];   // 3 x 24576; epilogue aliases bufs 0-1
    float* Ep = (float*)smem;        // [32][260] f32 = 33280 B

    const int tid = threadIdx.x;
    // bijective XCD-chunked remap, bn-major (bm fastest)
    int nwg = tiles_m * tiles_n;
    int q = nwg >> 3, r = nwg & 7;
    int xcd = blockIdx.x & 7, idx = blockIdx.x >> 3;
    int wg = (xcd < r ? xcd * (q + 1) : r * (q + 1) + (xcd - r) * q) + idx;
    int bn = wg / tiles_m;
    int bm = wg % tiles_m;

    const int wv = tid >> 6;
    const int lane = tid & 63;
    const int wr = wv >> 2;        // 0..1 (M half: 64 rows)
    const int wc = wv & 3;         // 0..3 (N quarter: 64 cols)
    const int lrow = lane & 15;
    const int kg = lane >> 4;      // 0..3 (16B k-slice)
    const int kgx = kg ^ (lrow & 3);  // swizzled slot for frag reads

    f32x4 acc[4][4];
#pragma unroll
    for (int i = 0; i < 4; ++i)
#pragma unroll
        for (int j = 0; j < 4; ++j) acc[i][j] = (f32x4){0.f, 0.f, 0.f, 0.f};

    const size_t rowb = (size_t)K * 2;
    const char* Ab = (const char*)A + (size_t)(bm * 128) * rowb;
    const char* Bb = (const char*)B + (size_t)(bn * 256) * rowb;

    // stage K-slab kk (32 wide) into buffer bufi: lane-linear LDS dst,
    // granule-XOR'd global source within each 64B line.
    auto STAGE = [&](int bufi, int kk) {
        char* dA = smem + bufi * 24576;
        char* dB = dA + 8192;
        int k2 = kk << 1;
        {   // A: 512 slots, rows 0..127
            int s = tid;
            int row = s >> 2, ls = s & 3;
            int gsl = ls ^ (row & 3);
            __builtin_amdgcn_global_load_lds(
                (const __attribute__((address_space(1))) void*)(Ab + (size_t)row * rowb + k2 + gsl * 16),
                (__attribute__((address_space(3))) void*)(dA + s * 16), 16, 0, 0);
        }
#pragma unroll
        for (int j = 0; j < 2; ++j) {  // B: 1024 slots, rows 0..255
            int s = j * 512 + tid;
            int row = s >> 2, ls = s & 3;
            int gsl = ls ^ (row & 3);
            __builtin_amdgcn_global_load_lds(
                (const __attribute__((address_space(1))) void*)(Bb + (size_t)row * rowb + k2 + gsl * 16),
                (__attribute__((address_space(3))) void*)(dB + s * 16), 16, 0, 0);
        }
    };

    auto COMPUTE = [&](int bufi) {
        const char* Ah = smem + bufi * 24576;
        const char* Bh = Ah + 8192;
        short8 a[4], b[4];
#pragma unroll
        for (int mi = 0; mi < 4; ++mi) {
            int rr = wr * 64 + mi * 16 + lrow;   // rr&3 == lrow&3
            a[mi] = *(const short8*)(Ah + rr * 64 + kgx * 16);
        }
#pragma unroll
        for (int ni = 0; ni < 4; ++ni) {
            int rr = wc * 64 + ni * 16 + lrow;
            b[ni] = *(const short8*)(Bh + rr * 64 + kgx * 16);
        }
        __builtin_amdgcn_s_setprio(1);
#pragma unroll
        for (int mi = 0; mi < 4; ++mi)
#pragma unroll
            for (int ni = 0; ni < 4; ++ni)
                acc[mi][ni] = __builtin_amdgcn_mfma_f32_16x16x32_bf16(a[mi], b[ni], acc[mi][ni], 0, 0, 0);
        __builtin_amdgcn_s_setprio(0);
    };

    const int nt = K >> 5;   // BK=32 tiles (16 at K=512)
    STAGE(0, 0);
    STAGE(1, 32);

    for (int t = 0; t < nt; ++t) {
        // drain stage(t); keep stage(t+1), stage(t+2) in flight
        if (t < nt - 1) asm volatile("s_waitcnt vmcnt(3)" ::: "memory");
        else            asm volatile("s_waitcnt vmcnt(0)" ::: "memory");
        __builtin_amdgcn_s_barrier();      // also fences buf(t+2)%3 reads (iter t-1)
        __builtin_amdgcn_sched_barrier(0);
        if (t + 2 < nt) STAGE((t + 2) % 3, (t + 2) << 5);
        COMPUTE(t % 3);
    }

    // bias (after loop: keeps the K-loop VMEM FIFO = stages only)
    float bv[4];
#pragma unroll
    for (int ni = 0; ni < 4; ++ni) {
        int col = bn * 256 + wc * 64 + ni * 16 + lrow;
        bv[ni] = (col < N) ? bias[col] : 0.f;
    }
    __syncthreads();  // all frag reads done before Ep overwrites LDS

    // Epilogue: 4 chunks of 32 rows x 256 cols.
#pragma unroll
    for (int ch = 0; ch < 4; ++ch) {
        if (wr == (ch >> 1)) {
#pragma unroll
            for (int m2 = 0; m2 < 2; ++m2) {
                int mi = (ch & 1) * 2 + m2;
#pragma unroll
                for (int ni = 0; ni < 4; ++ni) {
                    int c = wc * 64 + ni * 16 + lrow;
                    f32x4 v = acc[mi][ni];
#pragma unroll
                    for (int j = 0; j < 4; ++j)
                        Ep[(m2 * 16 + kg * 4 + j) * 260 + c] = v[j] + bv[ni];
                }
            }
        }
        __syncthreads();
        // 8 waves store 4 rows each; 64 lanes x 16B = full 1KB row
#pragma unroll
        for (int rr = 0; rr < 4; ++rr) {
            int rl = wv * 4 + rr;
            int grow = bm * 128 + ch * 32 + rl;
            int gc0 = bn * 256 + lane * 4;
            f32x4 v = *(const f32x4*)&Ep[rl * 260 + lane * 4];
            if (gc0 + 3 < N) {
                __builtin_nontemporal_store(v, (f32x4*)&C[(size_t)grow * N + gc0]);
            } else {
#pragma unroll
                for (int e = 0; e < 4; ++e)
                    if (gc0 + e < N)
                        __builtin_nontemporal_store(v[e], &C[(size_t)grow * N + gc0 + e]);
            }
        }
        if (ch < 3) __syncthreads();
    }
}

extern "C" void kernel_launch(void* const* d_in, const int* in_sizes, int n_in,
                              void* d_out, int out_size, void* d_ws, size_t ws_size,
                              hipStream_t stream) {
    const int* x    = (const int*)d_in[0];
    const float* emb = (const float*)d_in[1];
    const float* pos = (const float*)d_in[2];
    const float* b1 = (const float*)d_in[3];
    const float* b2 = (const float*)d_in[4];
    const float* b3 = (const float*)d_in[5];
    const float* w2 = (const float*)d_in[6];
    const float* fb2 = (const float*)d_in[7];
    const float* w3 = (const float*)d_in[8];
    const float* fb3 = (const float*)d_in[9];
    const float* wo = (const float*)d_in[10];
    const float* fbo = (const float*)d_in[11];
    float* out = (float*)d_out;

    const int V = 50257;
    const int TN = 197;                 // 256-col tiles for vocab
    const int Vpad = TN * 256;          // 50432

    static bool lds_cap_set = false;
    if (!lds_cap_set) {
        hipFuncSetAttribute((const void*)gemm_bt_v,
                            hipFuncAttributeMaxDynamicSharedMemorySize, 73728);
        lds_cap_set = true;
    }

    // workspace layout
    char* p = (char*)d_ws;
    u16* WO = (u16*)p;  p += (size_t)Vpad * 512 * 2;   // 51.6 MB
    u16* W2 = (u16*)p;  p += (size_t)512 * 512 * 2;
    u16* W3 = (u16*)p;  p += (size_t)512 * 512 * 2;
    u16* Abf = (u16*)p; p += (size_t)4096 * 512 * 2;   // bf16 activations [4096,512]
    float* Hb = (float*)p;                             // f32 activations [4096,512]

    // weight conversions f32 -> bf16 (merged)
    cvt3_kernel<<<dim3(2048), dim3(256), 0, stream>>>(
        wo, WO, V * 512 / 4, w2, W2, 512 * 512 / 4, w3, W3, 512 * 512 / 4);

    // embed + pos + leaky1 -> Abf
    embed_leaky_kernel<<<dim3(256), dim3(64), 0, stream>>>(x, emb, pos, b1, Abf);

    // fc2 + relu -> Hb
    gemm_bt_128<true><<<dim3(32 * 4), dim3(256), 0, stream>>>(Abf, W2, fb2, Hb, 4096, 512, 512, 4);
    // leaky2 -> Abf
    leaky_bf16_kernel<<<dim3(256), dim3(64), 0, stream>>>(Hb, b2, Abf);
    // fc3 + relu -> Hb
    gemm_bt_128<true><<<dim3(32 * 4), dim3(256), 0, stream>>>(Abf, W3, fb3, Hb, 4096, 512, 512, 4);
    // leaky3 -> Abf
    leaky_bf16_kernel<<<dim3(256), dim3(64), 0, stream>>>(Hb, b3, Abf);
    // vocab projection -> out: 128x256 tile, tri-buffer BK=32, 2 blocks/CU
    gemm_bt_v<<<dim3(32 * TN), dim3(512), 73728, stream>>>(Abf, WO, fbo, out, 4096, V, 512, 32, TN);
}